// Round 3
// baseline (810.556 us; speedup 1.0000x reference)
//
#include <hip/hip_runtime.h>

// VectorQuantizer: B=65536 rows, D=256, K=1024 codes.
// d_in[0] = inputs (B,D) fp32 ; d_in[1] = W (K,D) fp32
// d_out = [quantized_st (B*D)] [loss] [perplexity]  (fp32)
//
// argmin_k (||w_k||^2 - 2 x.w_k) via fp16 MFMA (fp32 accum).
// W pre-packed in MFMA B-fragment order (512 KB, L2-resident): B fragments
// are 1KB coalesced L2 loads, register-prefetched 2 k-slices ahead; zero
// barriers in the K-loop. X staged once in LDS as fp16 (64 rows/block,
// 36 KB LDS -> 4 blocks/CU = 4 waves/SIMD for latency hiding).
// quantized_st == W[idx] numerically; loss from fp16 Xs (abs err ~2e-3,
// scalar threshold ~19.6). Finalize fused via last-block done-counter.

using h16   = _Float16;
using h16x8 = __attribute__((ext_vector_type(8))) _Float16;
using h16x4 = __attribute__((ext_vector_type(4))) _Float16;
using f32x4 = __attribute__((ext_vector_type(4))) float;

#define W_SCALE 1024.0f          // keep fp16 W out of denormal range
#define W_UNSCALE2 0.001953125f  // 2 / 1024, exact power of two
#define XS_STRIDE 264            // 256 + 8 halves pad

// ---------------- kernel 1: pack W -> fp16 fragment-order + ||w||^2 + ws init ----------------
// Packed layout: Whp[((tile*8 + ks)*64 + quad*16 + lm)*8 + j]
//   = W_scaled[code = tile*16 + lm][d = ks*32 + quad*8 + j]
__global__ __launch_bounds__(64) void vq_wconv(const float* __restrict__ W,
                                               h16* __restrict__ Whp,
                                               float* __restrict__ wws,
                                               int* __restrict__ wsInit) {
  const int t = threadIdx.x;
  if (blockIdx.x == 0) {  // zero loss_sum, done, counts (bytes 0..4351 of ws)
#pragma unroll
    for (int i = 0; i < 17; ++i) wsInit[i * 64 + t] = 0;
  }
  const int code = blockIdx.x * 2 + (t >> 5);  // 2 codes per block
  const int j = t & 31;                        // d-group of 8
  const int d0 = j * 8;
  float4 v0 = *(const float4*)(W + (size_t)code * 256 + d0);
  float4 v1 = *(const float4*)(W + (size_t)code * 256 + d0 + 4);
  h16x8 h;
  h[0] = (h16)(v0.x * W_SCALE); h[1] = (h16)(v0.y * W_SCALE);
  h[2] = (h16)(v0.z * W_SCALE); h[3] = (h16)(v0.w * W_SCALE);
  h[4] = (h16)(v1.x * W_SCALE); h[5] = (h16)(v1.y * W_SCALE);
  h[6] = (h16)(v1.z * W_SCALE); h[7] = (h16)(v1.w * W_SCALE);
  const int tile = code >> 4, ks = j >> 2, quad = j & 3, lm = code & 15;
  *(h16x8*)(Whp + (size_t)(((tile * 8 + ks) * 64 + quad * 16 + lm) * 8)) = h;
  float ss = v0.x * v0.x + v0.y * v0.y + v0.z * v0.z + v0.w * v0.w
           + v1.x * v1.x + v1.y * v1.y + v1.z * v1.z + v1.w * v1.w;
#pragma unroll
  for (int m = 1; m <= 16; m <<= 1) ss += __shfl_xor(ss, m);  // within 32-lane half
  if (j == 0) wws[code] = ss;
}

// ---------------- kernel 2: scores + argmin + output + loss + histogram + finalize ----------------
// Block: 64 rows x all 1024 codes, 256 threads = 4 waves, grid 1024 (=4/CU exactly).
// Per chunk (128 codes): wave w covers n-tiles {chunk*8 + w*2, +1}, 4 m-tiles.
// mfma_f32_16x16x32_f16: A[m=lm][k=quad*8+j], B[k=quad*8+j][n=lm],
//                        D[row=quad*4+reg][col=lm]  (verified round 1)
__global__ __launch_bounds__(256, 4) void vq_main(const float* __restrict__ X,
                                                  const h16* __restrict__ Whp,
                                                  const float* __restrict__ wws,
                                                  const float* __restrict__ W,
                                                  float* __restrict__ out,
                                                  float* __restrict__ loss_sum,
                                                  int* __restrict__ done,
                                                  int* __restrict__ counts) {
  __shared__ h16 Xs[64 * XS_STRIDE];  // 33792 B
  __shared__ float redS[4 * 64];      // 1 KB (reused for final entropy reduce)
  __shared__ int redC[4 * 64];        // 1 KB
  __shared__ int sIdx[64];            // 256 B   (total 36096 B -> 4 blocks/CU)
  __shared__ int lastFlag;
  const int tid = threadIdx.x;
  const int lane = tid & 63;
  const int wid = tid >> 6;
  const int lm = lane & 15;
  const int quad = lane >> 4;
  const int rowBase = blockIdx.x * 64;

  // stage X tile: 64 rows x 256 d, fp32 -> fp16, 16B LDS writes
#pragma unroll
  for (int it = 0; it < 8; ++it) {
    int q = it * 256 + tid;
    int r = q >> 5;
    int dp = (q & 31) << 3;
    float4 v0 = *(const float4*)(X + (size_t)(rowBase + r) * 256 + dp);
    float4 v1 = *(const float4*)(X + (size_t)(rowBase + r) * 256 + dp + 4);
    h16x8 h;
    h[0] = (h16)v0.x; h[1] = (h16)v0.y; h[2] = (h16)v0.z; h[3] = (h16)v0.w;
    h[4] = (h16)v1.x; h[5] = (h16)v1.y; h[6] = (h16)v1.z; h[7] = (h16)v1.w;
    *(h16x8*)(Xs + r * XS_STRIDE + dp) = h;
  }
  __syncthreads();  // only barrier before epilogue

  // running best per row-slot: slot = mt*4+reg -> row = mt*16 + quad*4 + reg
  float bestS[16];
  int bestC[16];
#pragma unroll
  for (int s = 0; s < 16; ++s) { bestS[s] = 3.4e38f; bestC[s] = 0x7fffffff; }

  for (int chunk = 0; chunk < 8; ++chunk) {
    const int tbase = chunk * 8 + wid * 2;  // this wave's first n-tile
    const h16* bptr = Whp + (size_t)tbase * 4096 + lane * 8;
    f32x4 acc[4][2];
#pragma unroll
    for (int mt = 0; mt < 4; ++mt)
#pragma unroll
      for (int nt = 0; nt < 2; ++nt) {
        f32x4 z = {0.0f, 0.0f, 0.0f, 0.0f};
        acc[mt][nt] = z;
      }

    // register prefetch of B, distance 2 k-slices (L2 latency ~300 cyc)
    h16x8 bc0 = *(const h16x8*)(bptr);
    h16x8 bc1 = *(const h16x8*)(bptr + 4096);
    h16x8 bn0 = *(const h16x8*)(bptr + 512);
    h16x8 bn1 = *(const h16x8*)(bptr + 4096 + 512);
#pragma unroll
    for (int ks = 0; ks < 8; ++ks) {
      h16x8 u0 = bc0, u1 = bc1;
      bc0 = bn0; bc1 = bn1;
      if (ks < 6) {
        bn0 = *(const h16x8*)(bptr + (ks + 2) * 512);
        bn1 = *(const h16x8*)(bptr + 4096 + (ks + 2) * 512);
      }
      const int doff = ks * 32 + quad * 8;
#pragma unroll
      for (int mt = 0; mt < 4; ++mt) {
        h16x8 a = *(const h16x8*)(Xs + (mt * 16 + lm) * XS_STRIDE + doff);
        acc[mt][0] = __builtin_amdgcn_mfma_f32_16x16x32_f16(a, u0, acc[mt][0], 0, 0, 0);
        acc[mt][1] = __builtin_amdgcn_mfma_f32_16x16x32_f16(a, u1, acc[mt][1], 0, 0, 0);
      }
    }

    // epilogue: score = ||w||^2 - 2*dot ; fold into running best
#pragma unroll
    for (int nt = 0; nt < 2; ++nt) {
      int code = (tbase + nt) * 16 + lm;
      float wn = wws[code];
#pragma unroll
      for (int mt = 0; mt < 4; ++mt)
#pragma unroll
        for (int reg = 0; reg < 4; ++reg) {
          float s = fmaf(-W_UNSCALE2, acc[mt][nt][reg], wn);
          int slot = mt * 4 + reg;
          if (s < bestS[slot]) { bestS[slot] = s; bestC[slot] = code; }
        }
    }
  }

  // reduce across the 16 lanes of each quad (same rows, different codes)
#pragma unroll
  for (int m = 1; m <= 8; m <<= 1) {
#pragma unroll
    for (int s = 0; s < 16; ++s) {
      float os = __shfl_xor(bestS[s], m);
      int oc = __shfl_xor(bestC[s], m);
      if (os < bestS[s] || (os == bestS[s] && oc < bestC[s])) { bestS[s] = os; bestC[s] = oc; }
    }
  }
  if (lm == 0) {
#pragma unroll
    for (int s = 0; s < 16; ++s) {
      int row = (s >> 2) * 16 + quad * 4 + (s & 3);
      redS[wid * 64 + row] = bestS[s];
      redC[wid * 64 + row] = bestC[s];
    }
  }
  __syncthreads();
  if (tid < 64) {
    float b = 3.4e38f;
    int c = 0x7fffffff;
#pragma unroll
    for (int w = 0; w < 4; ++w) {
      float s = redS[w * 64 + tid];
      int cc = redC[w * 64 + tid];
      if (s < b || (s == b && cc < c)) { b = s; c = cc; }
    }
    sIdx[tid] = c;
    atomicAdd(&counts[c], 1);
  }
  __syncthreads();

  // output: out row = W[idx] (== x + sg(q-x) numerically); loss from fp16 Xs.
  float ll = 0.0f;
  const int d4 = lane << 2;
#pragma unroll 2
  for (int i = 0; i < 16; ++i) {
    int row = wid * 16 + i;
    int idx = sIdx[row];
    float4 qv = *(const float4*)(W + (size_t)idx * 256 + d4);
    h16x4 xh = *(const h16x4*)(Xs + row * XS_STRIDE + d4);
    float dx0 = qv.x - (float)xh[0];
    float dx1 = qv.y - (float)xh[1];
    float dx2 = qv.z - (float)xh[2];
    float dx3 = qv.w - (float)xh[3];
    ll += dx0 * dx0 + dx1 * dx1 + dx2 * dx2 + dx3 * dx3;
    *(float4*)(out + (size_t)(rowBase + row) * 256 + d4) = qv;
  }
#pragma unroll
  for (int m = 1; m <= 32; m <<= 1) ll += __shfl_xor(ll, m);
  if (lane == 0) atomicAdd(loss_sum, ll);

  // fused finalize: last block computes loss + perplexity
  __threadfence();
  if (tid == 0) {
    int old = atomicAdd(done, 1);
    lastFlag = (old == (int)gridDim.x - 1);
  }
  __syncthreads();
  if (lastFlag) {
    float h = 0.0f;
#pragma unroll
    for (int k = tid; k < 1024; k += 256) {
      int cnt = __hip_atomic_load(&counts[k], __ATOMIC_RELAXED, __HIP_MEMORY_SCOPE_AGENT);
      float p = (float)cnt * (1.0f / 65536.0f);
      h += p * logf(p + 1e-10f);
    }
    redS[tid] = h;
    __syncthreads();
#pragma unroll
    for (int s = 128; s > 0; s >>= 1) {
      if (tid < s) redS[tid] += redS[tid + s];
      __syncthreads();
    }
    if (tid == 0) {
      float ls = __hip_atomic_load(loss_sum, __ATOMIC_RELAXED, __HIP_MEMORY_SCOPE_AGENT);
      out[16777216] = ls * (1.25f / 16777216.0f);  // (1+0.25)*mean((q-x)^2)
      out[16777217] = expf(-redS[0]);
    }
  }
}

// ---------------- launch ----------------
extern "C" void kernel_launch(void* const* d_in, const int* in_sizes, int n_in,
                              void* d_out, int out_size, void* d_ws, size_t ws_size,
                              hipStream_t stream) {
  (void)in_sizes; (void)n_in; (void)out_size; (void)ws_size;
  const float* X = (const float*)d_in[0];
  const float* W = (const float*)d_in[1];
  float* out = (float*)d_out;
  char* ws = (char*)d_ws;
  // ws layout (bytes): [0] loss_sum f32 | [4] done i32 | [256] counts i32[1024]
  //                    [4352] wws f32[1024] | [8448] Whp f16[262144]  => 532736 total
  float* loss_sum = (float*)ws;
  int* done = (int*)(ws + 4);
  int* counts = (int*)(ws + 256);
  float* wws = (float*)(ws + 4352);
  h16* Whp = (h16*)(ws + 8448);

  vq_wconv<<<512, 64, 0, stream>>>(W, Whp, wws, (int*)ws);
  vq_main<<<1024, 256, 0, stream>>>(X, Whp, wws, W, out, loss_sum, done, counts);
}

// Round 4
// 359.976 us; speedup vs baseline: 2.2517x; 2.2517x over previous
//
#include <hip/hip_runtime.h>

// VectorQuantizer: B=65536 rows, D=256, K=1024 codes.
// d_in[0] = inputs (B,D) fp32 ; d_in[1] = W (K,D) fp32
// d_out = [quantized_st (B*D)] [loss] [perplexity]  (fp32)
//
// argmin_k (||w_k||^2 - 2 x.w_k) via fp16 MFMA (fp32 accum).
// W pre-packed in MFMA B-fragment order (512 KB, L2-resident): B fragments
// are 1KB coalesced L2 loads, register-prefetched 2 k-slices ahead; zero
// barriers in the K-loop. X staged once in LDS as fp16 (64 rows/block,
// 36 KB LDS). Argmin state is a single packed u32 key per row-slot
// ((biased-score high bits)|code) -> v_min_u32 updates, 16 regs not 32.
// Round-3 lesson: forcing waves-per-eu=4 (VGPR cap 128) spilled ~2.2 GB of
// scratch; use (256,3) so the allocator has slack, natural alloc ~110 still
// reaches 4 waves/EU at runtime.
// quantized_st == W[idx] numerically; loss from fp16 Xs (abs err ~2e-3,
// scalar threshold ~19.6). Finalize fused via last-block done-counter.

using h16   = _Float16;
using h16x8 = __attribute__((ext_vector_type(8))) _Float16;
using h16x4 = __attribute__((ext_vector_type(4))) _Float16;
using f32x4 = __attribute__((ext_vector_type(4))) float;

#define W_SCALE 1024.0f          // keep fp16 W out of denormal range
#define W_UNSCALE2 0.001953125f  // 2 / 1024, exact power of two
#define SCORE_BIAS 0.25f         // scores in [-0.06,0.06] -> biased always >0
#define XS_STRIDE 264            // 256 + 8 halves pad

// ---------------- kernel 1: pack W -> fp16 fragment-order + ||w||^2 + ws init ----------------
// Packed layout: Whp[((tile*8 + ks)*64 + quad*16 + lm)*8 + j]
//   = W_scaled[code = tile*16 + lm][d = ks*32 + quad*8 + j]
__global__ __launch_bounds__(64) void vq_wconv(const float* __restrict__ W,
                                               h16* __restrict__ Whp,
                                               float* __restrict__ wws,
                                               int* __restrict__ wsInit) {
  const int t = threadIdx.x;
  if (blockIdx.x == 0) {  // zero loss_sum, done, counts (bytes 0..4351 of ws)
#pragma unroll
    for (int i = 0; i < 17; ++i) wsInit[i * 64 + t] = 0;
  }
  const int code = blockIdx.x * 2 + (t >> 5);  // 2 codes per block
  const int j = t & 31;                        // d-group of 8
  const int d0 = j * 8;
  float4 v0 = *(const float4*)(W + (size_t)code * 256 + d0);
  float4 v1 = *(const float4*)(W + (size_t)code * 256 + d0 + 4);
  h16x8 h;
  h[0] = (h16)(v0.x * W_SCALE); h[1] = (h16)(v0.y * W_SCALE);
  h[2] = (h16)(v0.z * W_SCALE); h[3] = (h16)(v0.w * W_SCALE);
  h[4] = (h16)(v1.x * W_SCALE); h[5] = (h16)(v1.y * W_SCALE);
  h[6] = (h16)(v1.z * W_SCALE); h[7] = (h16)(v1.w * W_SCALE);
  const int tile = code >> 4, ks = j >> 2, quad = j & 3, lm = code & 15;
  *(h16x8*)(Whp + (size_t)(((tile * 8 + ks) * 64 + quad * 16 + lm) * 8)) = h;
  float ss = v0.x * v0.x + v0.y * v0.y + v0.z * v0.z + v0.w * v0.w
           + v1.x * v1.x + v1.y * v1.y + v1.z * v1.z + v1.w * v1.w;
#pragma unroll
  for (int m = 1; m <= 16; m <<= 1) ss += __shfl_xor(ss, m);  // within 32-lane half
  if (j == 0) wws[code] = ss + SCORE_BIAS;  // pre-biased for packed-key argmin
}

// ---------------- kernel 2: scores + argmin + output + loss + histogram + finalize ----------------
// Block: 64 rows x all 1024 codes, 256 threads = 4 waves, grid 1024 (=4/CU exactly).
// Per chunk (128 codes): wave w covers n-tiles {chunk*8 + w*2, +1}, 4 m-tiles.
// mfma_f32_16x16x32_f16: A[m=lm][k=quad*8+j], B[k=quad*8+j][n=lm],
//                        D[row=quad*4+reg][col=lm]  (verified round 1)
__global__ __launch_bounds__(256, 3) void vq_main(const float* __restrict__ X,
                                                  const h16* __restrict__ Whp,
                                                  const float* __restrict__ wws,
                                                  const float* __restrict__ W,
                                                  float* __restrict__ out,
                                                  float* __restrict__ loss_sum,
                                                  int* __restrict__ done,
                                                  int* __restrict__ counts) {
  __shared__ h16 Xs[64 * XS_STRIDE];   // 33792 B
  __shared__ unsigned redK[4 * 64];    // 1 KB (reused for final entropy reduce)
  __shared__ int sIdx[64];             // 256 B  (total ~35 KB -> 4 blocks/CU)
  __shared__ int lastFlag;
  const int tid = threadIdx.x;
  const int lane = tid & 63;
  const int wid = tid >> 6;
  const int lm = lane & 15;
  const int quad = lane >> 4;
  const int rowBase = blockIdx.x * 64;

  // stage X tile: 64 rows x 256 d, fp32 -> fp16, 16B LDS writes
#pragma unroll
  for (int it = 0; it < 8; ++it) {
    int q = it * 256 + tid;
    int r = q >> 5;
    int dp = (q & 31) << 3;
    float4 v0 = *(const float4*)(X + (size_t)(rowBase + r) * 256 + dp);
    float4 v1 = *(const float4*)(X + (size_t)(rowBase + r) * 256 + dp + 4);
    h16x8 h;
    h[0] = (h16)v0.x; h[1] = (h16)v0.y; h[2] = (h16)v0.z; h[3] = (h16)v0.w;
    h[4] = (h16)v1.x; h[5] = (h16)v1.y; h[6] = (h16)v1.z; h[7] = (h16)v1.w;
    *(h16x8*)(Xs + r * XS_STRIDE + dp) = h;
  }
  __syncthreads();  // only barrier before epilogue

  // running best per row-slot as packed key (score-hi-bits | code):
  // slot = mt*4+reg -> row = mt*16 + quad*4 + reg
  unsigned bestK[16];
#pragma unroll
  for (int s = 0; s < 16; ++s) bestK[s] = 0xFFFFFFFFu;

  for (int chunk = 0; chunk < 8; ++chunk) {
    const int tbase = chunk * 8 + wid * 2;  // this wave's first n-tile
    const h16* bptr = Whp + (size_t)tbase * 4096 + lane * 8;
    f32x4 acc[4][2];
#pragma unroll
    for (int mt = 0; mt < 4; ++mt)
#pragma unroll
      for (int nt = 0; nt < 2; ++nt) {
        f32x4 z = {0.0f, 0.0f, 0.0f, 0.0f};
        acc[mt][nt] = z;
      }

    // register prefetch of B, distance 2 k-slices (L2 latency ~300 cyc)
    h16x8 bc0 = *(const h16x8*)(bptr);
    h16x8 bc1 = *(const h16x8*)(bptr + 4096);
    h16x8 bn0 = *(const h16x8*)(bptr + 512);
    h16x8 bn1 = *(const h16x8*)(bptr + 4096 + 512);
#pragma unroll
    for (int ks = 0; ks < 8; ++ks) {
      h16x8 u0 = bc0, u1 = bc1;
      bc0 = bn0; bc1 = bn1;
      if (ks < 6) {
        bn0 = *(const h16x8*)(bptr + (ks + 2) * 512);
        bn1 = *(const h16x8*)(bptr + 4096 + (ks + 2) * 512);
      }
      const int doff = ks * 32 + quad * 8;
#pragma unroll
      for (int mt = 0; mt < 4; ++mt) {
        h16x8 a = *(const h16x8*)(Xs + (mt * 16 + lm) * XS_STRIDE + doff);
        acc[mt][0] = __builtin_amdgcn_mfma_f32_16x16x32_f16(a, u0, acc[mt][0], 0, 0, 0);
        acc[mt][1] = __builtin_amdgcn_mfma_f32_16x16x32_f16(a, u1, acc[mt][1], 0, 0, 0);
      }
    }

    // epilogue: biased score = (||w||^2+0.25) - 2*dot  (always > 0 ->
    // float_as_uint monotonic); fold (score|code) into running min-key.
#pragma unroll
    for (int nt = 0; nt < 2; ++nt) {
      int code = (tbase + nt) * 16 + lm;
      float wn = wws[code];
#pragma unroll
      for (int mt = 0; mt < 4; ++mt)
#pragma unroll
        for (int reg = 0; reg < 4; ++reg) {
          float s = fmaf(-W_UNSCALE2, acc[mt][nt][reg], wn);
          unsigned key = (__float_as_uint(s) & 0xFFFFFC00u) | (unsigned)code;
          int slot = mt * 4 + reg;
          bestK[slot] = min(bestK[slot], key);
        }
    }
  }

  // reduce across the 16 lanes of each quad (same rows, different codes)
#pragma unroll
  for (int m = 1; m <= 8; m <<= 1) {
#pragma unroll
    for (int s = 0; s < 16; ++s) {
      unsigned ok = __shfl_xor(bestK[s], m);
      bestK[s] = min(bestK[s], ok);
    }
  }
  if (lm == 0) {
#pragma unroll
    for (int s = 0; s < 16; ++s) {
      int row = (s >> 2) * 16 + quad * 4 + (s & 3);
      redK[wid * 64 + row] = bestK[s];
    }
  }
  __syncthreads();
  if (tid < 64) {
    unsigned b = 0xFFFFFFFFu;
#pragma unroll
    for (int w = 0; w < 4; ++w) b = min(b, redK[w * 64 + tid]);
    int c = (int)(b & 1023u);
    sIdx[tid] = c;
    atomicAdd(&counts[c], 1);
  }
  __syncthreads();

  // output: out row = W[idx] (== x + sg(q-x) numerically); loss from fp16 Xs.
  float ll = 0.0f;
  const int d4 = lane << 2;
#pragma unroll 2
  for (int i = 0; i < 16; ++i) {
    int row = wid * 16 + i;
    int idx = sIdx[row];
    float4 qv = *(const float4*)(W + (size_t)idx * 256 + d4);
    h16x4 xh = *(const h16x4*)(Xs + row * XS_STRIDE + d4);
    float dx0 = qv.x - (float)xh[0];
    float dx1 = qv.y - (float)xh[1];
    float dx2 = qv.z - (float)xh[2];
    float dx3 = qv.w - (float)xh[3];
    ll += dx0 * dx0 + dx1 * dx1 + dx2 * dx2 + dx3 * dx3;
    *(float4*)(out + (size_t)(rowBase + row) * 256 + d4) = qv;
  }
#pragma unroll
  for (int m = 1; m <= 32; m <<= 1) ll += __shfl_xor(ll, m);
  if (lane == 0) atomicAdd(loss_sum, ll);

  // fused finalize: last block computes loss + perplexity
  __threadfence();
  if (tid == 0) {
    int old = atomicAdd(done, 1);
    lastFlag = (old == (int)gridDim.x - 1);
  }
  __syncthreads();
  if (lastFlag) {
    float* redF = (float*)redK;
    float h = 0.0f;
#pragma unroll
    for (int k = tid; k < 1024; k += 256) {
      int cnt = __hip_atomic_load(&counts[k], __ATOMIC_RELAXED, __HIP_MEMORY_SCOPE_AGENT);
      float p = (float)cnt * (1.0f / 65536.0f);
      h += p * logf(p + 1e-10f);
    }
#pragma unroll
    for (int m = 1; m <= 32; m <<= 1) h += __shfl_xor(h, m);
    if (lane == 0) redF[wid] = h;
    __syncthreads();
    if (tid == 0) {
      float hs = redF[0] + redF[1] + redF[2] + redF[3];
      float ls = __hip_atomic_load(loss_sum, __ATOMIC_RELAXED, __HIP_MEMORY_SCOPE_AGENT);
      out[16777216] = ls * (1.25f / 16777216.0f);  // (1+0.25)*mean((q-x)^2)
      out[16777217] = expf(-hs);
    }
  }
}

// ---------------- launch ----------------
extern "C" void kernel_launch(void* const* d_in, const int* in_sizes, int n_in,
                              void* d_out, int out_size, void* d_ws, size_t ws_size,
                              hipStream_t stream) {
  (void)in_sizes; (void)n_in; (void)out_size; (void)ws_size;
  const float* X = (const float*)d_in[0];
  const float* W = (const float*)d_in[1];
  float* out = (float*)d_out;
  char* ws = (char*)d_ws;
  // ws layout (bytes): [0] loss_sum f32 | [4] done i32 | [256] counts i32[1024]
  //                    [4352] wws f32[1024] | [8448] Whp f16[262144]  => 532736 total
  float* loss_sum = (float*)ws;
  int* done = (int*)(ws + 4);
  int* counts = (int*)(ws + 256);
  float* wws = (float*)(ws + 4352);
  h16* Whp = (h16*)(ws + 8448);

  vq_wconv<<<512, 64, 0, stream>>>(W, Whp, wws, (int*)ws);
  vq_main<<<1024, 256, 0, stream>>>(X, Whp, wws, W, out, loss_sum, done, counts);
}